// Round 3
// baseline (623.361 us; speedup 1.0000x reference)
//
#include <hip/hip_runtime.h>
#include <math.h>

#define NLV 16
#define LOG2_T 19
#define T_SIZE (1u << LOG2_T)
#define T_MASK (T_SIZE - 1u)
#define P2 2654435761u
#define P3 805459861u
#define NBUCK 32768   // 32^3 Morton buckets

typedef float vf2 __attribute__((ext_vector_type(2)));
typedef float vf4 __attribute__((ext_vector_type(4)));

struct Scales { float s[NLV]; };

// ---------- Morton key (5 bits/axis) ----------
__device__ __forceinline__ unsigned mpart(unsigned v) {
    v = (v | (v << 8)) & 0x100Fu;
    v = (v | (v << 4)) & 0x10C3u;
    v = (v | (v << 2)) & 0x1249u;
    return v;
}
__device__ __forceinline__ unsigned mkey(float px, float py, float pz) {
    unsigned cx = (unsigned)(px * 32.f); cx = cx > 31u ? 31u : cx;
    unsigned cy = (unsigned)(py * 32.f); cy = cy > 31u ? 31u : cy;
    unsigned cz = (unsigned)(pz * 32.f); cz = cz > 31u ? 31u : cz;
    return mpart(cx) | (mpart(cy) << 1) | (mpart(cz) << 2);
}

// ---------- sort kernels ----------
__global__ __launch_bounds__(256) void zero_hist_kernel(unsigned* hist) {
    int i = blockIdx.x * 256 + threadIdx.x;
    if (i < NBUCK) hist[i] = 0u;
}

__global__ __launch_bounds__(256) void hist_kernel(
    const float* __restrict__ x, unsigned* __restrict__ hist, int N)
{
    int i = blockIdx.x * 256 + threadIdx.x;
    if (i >= N) return;
    const float px = x[3 * (size_t)i + 0];
    const float py = x[3 * (size_t)i + 1];
    const float pz = x[3 * (size_t)i + 2];
    atomicAdd(&hist[mkey(px, py, pz)], 1u);
}

__global__ __launch_bounds__(1024) void scan_kernel(unsigned* hist) {
    __shared__ unsigned tot[1024];
    const int t = threadIdx.x;
    const unsigned base = (unsigned)t * 32u;
    unsigned loc[32];
    unsigned s = 0;
    #pragma unroll
    for (int k = 0; k < 32; ++k) { loc[k] = s; s += hist[base + k]; }
    tot[t] = s;
    __syncthreads();
    for (int off = 1; off < 1024; off <<= 1) {
        unsigned u = (t >= off) ? tot[t - off] : 0u;
        __syncthreads();
        tot[t] += u;
        __syncthreads();
    }
    const unsigned excl = tot[t] - s;
    #pragma unroll
    for (int k = 0; k < 32; ++k) hist[base + k] = excl + loc[k];
}

__global__ __launch_bounds__(256) void scatter_kernel(
    const float* __restrict__ x, unsigned* __restrict__ cursor,
    vf4* __restrict__ xs, int* __restrict__ perm, int N)
{
    int i = blockIdx.x * 256 + threadIdx.x;
    if (i >= N) return;
    const float px = x[3 * (size_t)i + 0];
    const float py = x[3 * (size_t)i + 1];
    const float pz = x[3 * (size_t)i + 2];
    const unsigned key = mkey(px, py, pz);
    const unsigned pos = atomicAdd(&cursor[key], 1u);
    vf4 v; v[0] = px; v[1] = py; v[2] = pz; v[3] = 0.f;
    xs[pos] = v;
    perm[pos] = i;
}

// ---------- encode ----------
__device__ __forceinline__ void enc_level(
    float px, float py, float pz, float s, const float* __restrict__ tl,
    float& f0, float& f1)
{
    const float fx = px * s, fy = py * s, fz = pz * s;
    const float bx = floorf(fx), by = floorf(fy), bz = floorf(fz);
    const float rx = fx - bx, ry = fy - by, rz = fz - bz;
    const unsigned ix0 = (unsigned)bx, iy0 = (unsigned)by, iz0 = (unsigned)bz;
    const unsigned hx0 = ix0,      hx1 = ix0 + 1u;
    const unsigned hy0 = iy0 * P2, hy1 = (iy0 + 1u) * P2;
    const unsigned hz0 = iz0 * P3, hz1 = (iz0 + 1u) * P3;
    const float wx0 = 1.f - rx, wy0 = 1.f - ry, wz0 = 1.f - rz;
    f0 = 0.f; f1 = 0.f;
    #pragma unroll
    for (int c = 0; c < 8; ++c) {
        unsigned h = ((c & 4) ? hx1 : hx0) ^ ((c & 2) ? hy1 : hy0) ^ ((c & 1) ? hz1 : hz0);
        h &= T_MASK;
        const vf2 f = *(const vf2*)(tl + 2u * (size_t)h);
        const float w = ((c & 4) ? rx : wx0) * ((c & 2) ? ry : wy0) * ((c & 1) ? rz : wz0);
        f0 += w * f[0];
        f1 += w * f[1];
    }
}

__global__ __launch_bounds__(256) void encode_coarse_kernel(
    const vf4* __restrict__ xs, const float* __restrict__ table,
    float* __restrict__ enc, int N, Scales sc)
{
    int i = blockIdx.x * 256 + threadIdx.x;
    if (i >= N) return;
    const vf4 p = xs[i];
    #pragma unroll
    for (int l = 0; l < 5; ++l) {
        float f0, f1;
        enc_level(p[0], p[1], p[2], sc.s[l], table + (size_t)l * T_SIZE * 2u, f0, f1);
        vf2 v; v[0] = f0; v[1] = f1;
        __builtin_nontemporal_store(v, (vf2*)(enc + ((size_t)l * N + i) * 2u));
    }
}

__global__ __launch_bounds__(256) void encode_one_kernel(
    const vf4* __restrict__ xs, const float* __restrict__ tl, float s,
    float* __restrict__ encl, int N)
{
    int i = blockIdx.x * 256 + threadIdx.x;
    if (i >= N) return;
    const vf4 p = xs[i];
    float f0, f1;
    enc_level(p[0], p[1], p[2], s, tl, f0, f1);
    vf2 v; v[0] = f0; v[1] = f1;
    __builtin_nontemporal_store(v, (vf2*)(encl + (size_t)i * 2u));
}

// ---------- MLP (reads sorted enc, scatters to original slots) ----------
__global__ __launch_bounds__(256) void mlp_kernel(
    const float* __restrict__ enc, const int* __restrict__ perm,
    const float* __restrict__ W0, const float* __restrict__ b0,
    const float* __restrict__ W1, const float* __restrict__ b1,
    const float* __restrict__ W2, const float* __restrict__ b2,
    float* __restrict__ out, int N)
{
    int i = blockIdx.x * 256 + threadIdx.x;
    if (i >= N) return;

    float e[32];
    #pragma unroll
    for (int l = 0; l < NLV; ++l) {
        vf2 v = __builtin_nontemporal_load((const vf2*)(enc + ((size_t)l * N + i) * 2u));
        e[2 * l + 0] = v[0];
        e[2 * l + 1] = v[1];
    }

    float a0[16];
    #pragma unroll
    for (int j = 0; j < 16; ++j) {
        float s = b0[j];
        #pragma unroll
        for (int k = 0; k < 32; ++k) s += e[k] * W0[j * 32 + k];
        a0[j] = fmaxf(s, 0.f);
    }
    float a1[16];
    #pragma unroll
    for (int j = 0; j < 16; ++j) {
        float s = b1[j];
        #pragma unroll
        for (int k = 0; k < 16; ++k) s += a0[k] * W1[j * 16 + k];
        a1[j] = fmaxf(s, 0.f);
    }
    float o[16];
    #pragma unroll
    for (int j = 0; j < 16; ++j) {
        float s = b2[j];
        #pragma unroll
        for (int k = 0; k < 16; ++k) s += a1[k] * W2[j * 16 + k];
        o[j] = s;
    }

    float* op = out + 16 * (size_t)perm[i];
    #pragma unroll
    for (int q = 0; q < 4; ++q) {
        vf4 v; v[0] = o[4*q]; v[1] = o[4*q+1]; v[2] = o[4*q+2]; v[3] = o[4*q+3];
        __builtin_nontemporal_store(v, (vf4*)(op + 4 * q));
    }
}

// ---------- fallback paths ----------
__global__ __launch_bounds__(256) void encode_coarse_unsorted_kernel(
    const float* __restrict__ x, const float* __restrict__ table,
    float* __restrict__ enc, int N, Scales sc)
{
    int i = blockIdx.x * 256 + threadIdx.x;
    if (i >= N) return;
    const float px = x[3 * (size_t)i + 0];
    const float py = x[3 * (size_t)i + 1];
    const float pz = x[3 * (size_t)i + 2];
    #pragma unroll
    for (int l = 0; l < 5; ++l) {
        float f0, f1;
        enc_level(px, py, pz, sc.s[l], table + (size_t)l * T_SIZE * 2u, f0, f1);
        vf2 v; v[0] = f0; v[1] = f1;
        __builtin_nontemporal_store(v, (vf2*)(enc + ((size_t)l * N + i) * 2u));
    }
}
__global__ __launch_bounds__(256) void encode_one_unsorted_kernel(
    const float* __restrict__ x, const float* __restrict__ tl, float s,
    float* __restrict__ encl, int N)
{
    int i = blockIdx.x * 256 + threadIdx.x;
    if (i >= N) return;
    const float px = x[3 * (size_t)i + 0];
    const float py = x[3 * (size_t)i + 1];
    const float pz = x[3 * (size_t)i + 2];
    float f0, f1;
    enc_level(px, py, pz, s, tl, f0, f1);
    vf2 v; v[0] = f0; v[1] = f1;
    __builtin_nontemporal_store(v, (vf2*)(encl + (size_t)i * 2u));
}
__global__ __launch_bounds__(256) void mlp_noperm_kernel(
    const float* __restrict__ enc,
    const float* __restrict__ W0, const float* __restrict__ b0,
    const float* __restrict__ W1, const float* __restrict__ b1,
    const float* __restrict__ W2, const float* __restrict__ b2,
    float* __restrict__ out, int N)
{
    int i = blockIdx.x * 256 + threadIdx.x;
    if (i >= N) return;
    float e[32];
    #pragma unroll
    for (int l = 0; l < NLV; ++l) {
        vf2 v = __builtin_nontemporal_load((const vf2*)(enc + ((size_t)l * N + i) * 2u));
        e[2 * l + 0] = v[0];
        e[2 * l + 1] = v[1];
    }
    float a0[16];
    #pragma unroll
    for (int j = 0; j < 16; ++j) {
        float s = b0[j];
        #pragma unroll
        for (int k = 0; k < 32; ++k) s += e[k] * W0[j * 32 + k];
        a0[j] = fmaxf(s, 0.f);
    }
    float a1[16];
    #pragma unroll
    for (int j = 0; j < 16; ++j) {
        float s = b1[j];
        #pragma unroll
        for (int k = 0; k < 16; ++k) s += a0[k] * W1[j * 16 + k];
        a1[j] = fmaxf(s, 0.f);
    }
    #pragma unroll
    for (int j = 0; j < 16; ++j) {
        float s = b2[j];
        #pragma unroll
        for (int k = 0; k < 16; ++k) s += a1[k] * W2[j * 16 + k];
        out[16 * (size_t)i + j] = s;
    }
}
__global__ __launch_bounds__(256) void tcnn_fused_kernel(
    const float* __restrict__ x, const float* __restrict__ table,
    const float* __restrict__ W0, const float* __restrict__ b0,
    const float* __restrict__ W1, const float* __restrict__ b1,
    const float* __restrict__ W2, const float* __restrict__ b2,
    float* __restrict__ out, int N, Scales sc)
{
    int i = blockIdx.x * blockDim.x + threadIdx.x;
    if (i >= N) return;
    const float px = x[3 * (size_t)i + 0];
    const float py = x[3 * (size_t)i + 1];
    const float pz = x[3 * (size_t)i + 2];
    float e[32];
    #pragma unroll
    for (int l = 0; l < NLV; ++l) {
        float f0, f1;
        enc_level(px, py, pz, sc.s[l], table + (size_t)l * T_SIZE * 2u, f0, f1);
        e[2 * l] = f0; e[2 * l + 1] = f1;
    }
    float a0[16];
    #pragma unroll
    for (int j = 0; j < 16; ++j) {
        float s = b0[j];
        #pragma unroll
        for (int k = 0; k < 32; ++k) s += e[k] * W0[j * 32 + k];
        a0[j] = fmaxf(s, 0.f);
    }
    float a1[16];
    #pragma unroll
    for (int j = 0; j < 16; ++j) {
        float s = b1[j];
        #pragma unroll
        for (int k = 0; k < 16; ++k) s += a0[k] * W1[j * 16 + k];
        a1[j] = fmaxf(s, 0.f);
    }
    #pragma unroll
    for (int j = 0; j < 16; ++j) {
        float s = b2[j];
        #pragma unroll
        for (int k = 0; k < 16; ++k) s += a1[k] * W2[j * 16 + k];
        out[16 * (size_t)i + j] = s;
    }
}

extern "C" void kernel_launch(void* const* d_in, const int* in_sizes, int n_in,
                              void* d_out, int out_size, void* d_ws, size_t ws_size,
                              hipStream_t stream) {
    const float* x     = (const float*)d_in[0];
    const float* table = (const float*)d_in[1];
    const float* W0    = (const float*)d_in[2];
    const float* b0    = (const float*)d_in[3];
    const float* W1    = (const float*)d_in[4];
    const float* b1    = (const float*)d_in[5];
    const float* W2    = (const float*)d_in[6];
    const float* b2    = (const float*)d_in[7];
    float* out = (float*)d_out;

    const int N = in_sizes[0] / 3;

    Scales sc;
    const double pls = exp2(log2(2048.0 / 16.0) / 15.0);  // matches numpy double math
    for (int l = 0; l < NLV; ++l) sc.s[l] = (float)(16.0 * pow(pls, (double)l));

    const int block = 256;
    const int grid = (N + block - 1) / block;

    const size_t encB  = (size_t)N * 2u * NLV * sizeof(float);   // 128 MiB
    const size_t xsB   = (size_t)N * sizeof(float) * 4u;         //  16 MiB
    const size_t permB = (size_t)N * sizeof(int);                //   4 MiB
    const size_t histB = (size_t)NBUCK * sizeof(unsigned);

    if (ws_size >= encB + xsB + permB + histB) {
        float*    enc  = (float*)d_ws;
        vf4*      xs   = (vf4*)((char*)d_ws + encB);
        int*      perm = (int*)((char*)d_ws + encB + xsB);
        unsigned* hist = (unsigned*)((char*)d_ws + encB + xsB + permB);

        zero_hist_kernel<<<(NBUCK + 255) / 256, block, 0, stream>>>(hist);
        hist_kernel<<<grid, block, 0, stream>>>(x, hist, N);
        scan_kernel<<<1, 1024, 0, stream>>>(hist);
        scatter_kernel<<<grid, block, 0, stream>>>(x, hist, xs, perm, N);

        encode_coarse_kernel<<<grid, block, 0, stream>>>(xs, table, enc, N, sc);
        for (int l = 5; l < NLV; ++l) {
            encode_one_kernel<<<grid, block, 0, stream>>>(
                xs, table + (size_t)l * T_SIZE * 2u, sc.s[l],
                enc + (size_t)l * (size_t)N * 2u, N);
        }
        mlp_kernel<<<grid, block, 0, stream>>>(enc, perm, W0, b0, W1, b1, W2, b2, out, N);
    } else if (ws_size >= encB) {
        float* enc = (float*)d_ws;
        encode_coarse_unsorted_kernel<<<grid, block, 0, stream>>>(x, table, enc, N, sc);
        for (int l = 5; l < NLV; ++l) {
            encode_one_unsorted_kernel<<<grid, block, 0, stream>>>(
                x, table + (size_t)l * T_SIZE * 2u, sc.s[l],
                enc + (size_t)l * (size_t)N * 2u, N);
        }
        mlp_noperm_kernel<<<grid, block, 0, stream>>>(enc, W0, b0, W1, b1, W2, b2, out, N);
    } else {
        tcnn_fused_kernel<<<grid, block, 0, stream>>>(x, table, W0, b0, W1, b1, W2, b2,
                                                      out, N, sc);
    }
}

// Round 4
// 545.823 us; speedup vs baseline: 1.1421x; 1.1421x over previous
//
#include <hip/hip_runtime.h>
#include <math.h>

#define NLV 16
#define LOG2_T 19
#define T_SIZE (1u << LOG2_T)
#define T_MASK (T_SIZE - 1u)
#define P2 2654435761u
#define P3 805459861u
#define NBUCK 32768   // 32^3 Morton buckets

typedef float vf2 __attribute__((ext_vector_type(2)));
typedef float vf4 __attribute__((ext_vector_type(4)));

struct Scales { float s[NLV]; };

// ---------- Morton key (5 bits/axis) ----------
__device__ __forceinline__ unsigned mpart(unsigned v) {
    v = (v | (v << 8)) & 0x100Fu;
    v = (v | (v << 4)) & 0x10C3u;
    v = (v | (v << 2)) & 0x1249u;
    return v;
}
__device__ __forceinline__ unsigned mkey(float px, float py, float pz) {
    unsigned cx = (unsigned)(px * 32.f); cx = cx > 31u ? 31u : cx;
    unsigned cy = (unsigned)(py * 32.f); cy = cy > 31u ? 31u : cy;
    unsigned cz = (unsigned)(pz * 32.f); cz = cz > 31u ? 31u : cz;
    return mpart(cx) | (mpart(cy) << 1) | (mpart(cz) << 2);
}

// ---------- sort kernels ----------
__global__ __launch_bounds__(256) void zero_hist_kernel(unsigned* hist) {
    int i = blockIdx.x * 256 + threadIdx.x;
    if (i < NBUCK) hist[i] = 0u;
}

__global__ __launch_bounds__(256) void hist_kernel(
    const float* __restrict__ x, unsigned* __restrict__ hist, int N)
{
    int i = blockIdx.x * 256 + threadIdx.x;
    if (i >= N) return;
    const float px = x[3 * (size_t)i + 0];
    const float py = x[3 * (size_t)i + 1];
    const float pz = x[3 * (size_t)i + 2];
    atomicAdd(&hist[mkey(px, py, pz)], 1u);
}

__global__ __launch_bounds__(1024) void scan_kernel(unsigned* hist) {
    __shared__ unsigned tot[1024];
    const int t = threadIdx.x;
    const unsigned base = (unsigned)t * 32u;
    unsigned loc[32];
    unsigned s = 0;
    #pragma unroll
    for (int k = 0; k < 32; ++k) { loc[k] = s; s += hist[base + k]; }
    tot[t] = s;
    __syncthreads();
    for (int off = 1; off < 1024; off <<= 1) {
        unsigned u = (t >= off) ? tot[t - off] : 0u;
        __syncthreads();
        tot[t] += u;
        __syncthreads();
    }
    const unsigned excl = tot[t] - s;
    #pragma unroll
    for (int k = 0; k < 32; ++k) hist[base + k] = excl + loc[k];
}

__global__ __launch_bounds__(256) void scatter_kernel(
    const float* __restrict__ x, unsigned* __restrict__ cursor,
    vf4* __restrict__ xs, int* __restrict__ perm, int N)
{
    int i = blockIdx.x * 256 + threadIdx.x;
    if (i >= N) return;
    const float px = x[3 * (size_t)i + 0];
    const float py = x[3 * (size_t)i + 1];
    const float pz = x[3 * (size_t)i + 2];
    const unsigned key = mkey(px, py, pz);
    const unsigned pos = atomicAdd(&cursor[key], 1u);
    vf4 v; v[0] = px; v[1] = py; v[2] = pz; v[3] = 0.f;
    xs[pos] = v;
    perm[pos] = i;
}

// ---------- encode ----------
__device__ __forceinline__ void enc_level(
    float px, float py, float pz, float s, const float* __restrict__ tl,
    float& f0, float& f1)
{
    const float fx = px * s, fy = py * s, fz = pz * s;
    const float bx = floorf(fx), by = floorf(fy), bz = floorf(fz);
    const float rx = fx - bx, ry = fy - by, rz = fz - bz;
    const unsigned ix0 = (unsigned)bx, iy0 = (unsigned)by, iz0 = (unsigned)bz;
    const unsigned hx0 = ix0,      hx1 = ix0 + 1u;
    const unsigned hy0 = iy0 * P2, hy1 = (iy0 + 1u) * P2;
    const unsigned hz0 = iz0 * P3, hz1 = (iz0 + 1u) * P3;
    const float wx0 = 1.f - rx, wy0 = 1.f - ry, wz0 = 1.f - rz;
    f0 = 0.f; f1 = 0.f;
    #pragma unroll
    for (int c = 0; c < 8; ++c) {
        unsigned h = ((c & 4) ? hx1 : hx0) ^ ((c & 2) ? hy1 : hy0) ^ ((c & 1) ? hz1 : hz0);
        h &= T_MASK;
        const vf2 f = *(const vf2*)(tl + 2u * (size_t)h);
        const float w = ((c & 4) ? rx : wx0) * ((c & 2) ? ry : wy0) * ((c & 1) ? rz : wz0);
        f0 += w * f[0];
        f1 += w * f[1];
    }
}

// Levels 0..4 fused (working sets co-resident in L2).
__global__ __launch_bounds__(256) void encode_coarse_kernel(
    const vf4* __restrict__ xs, const float* __restrict__ table,
    float* __restrict__ enc, int N, Scales sc)
{
    int i = blockIdx.x * 256 + threadIdx.x;
    if (i >= N) return;
    const vf4 p = xs[i];
    #pragma unroll
    for (int l = 0; l < 5; ++l) {
        float f0, f1;
        enc_level(p[0], p[1], p[2], sc.s[l], table + (size_t)l * T_SIZE * 2u, f0, f1);
        vf2 v; v[0] = f0; v[1] = f1;
        __builtin_nontemporal_store(v, (vf2*)(enc + ((size_t)l * N + i) * 2u));
    }
}

// One fine level per launch; 2 points per thread for memory-level parallelism.
__global__ __launch_bounds__(256) void encode_one_kernel(
    const vf4* __restrict__ xs, const float* __restrict__ tl, float s,
    float* __restrict__ encl, int N)
{
    int i0 = blockIdx.x * 512 + threadIdx.x;
    int i1 = i0 + 256;
    if (i0 < N) {
        const vf4 p0 = xs[i0];
        const vf4 p1 = (i1 < N) ? xs[i1] : p0;
        float a0, a1, b0v, b1v;
        enc_level(p0[0], p0[1], p0[2], s, tl, a0, a1);
        enc_level(p1[0], p1[1], p1[2], s, tl, b0v, b1v);
        vf2 va; va[0] = a0; va[1] = a1;
        __builtin_nontemporal_store(va, (vf2*)(encl + (size_t)i0 * 2u));
        if (i1 < N) {
            vf2 vb; vb[0] = b0v; vb[1] = b1v;
            __builtin_nontemporal_store(vb, (vf2*)(encl + (size_t)i1 * 2u));
        }
    }
}

// ---------- MLP: compute per-thread, stage in LDS, cooperative 4-lanes/point store ----------
__global__ __launch_bounds__(256) void mlp_kernel(
    const float* __restrict__ enc, const int* __restrict__ perm,
    const float* __restrict__ W0, const float* __restrict__ b0,
    const float* __restrict__ W1, const float* __restrict__ b1,
    const float* __restrict__ W2, const float* __restrict__ b2,
    float* __restrict__ out, int N)
{
    __shared__ float st[256 * 17];   // padded rows: 17*t mod 32 bijective -> low conflicts
    const int base = blockIdx.x * 256;
    const int t = threadIdx.x;
    const int i = base + t;

    float o[16];
    if (i < N) {
        float e[32];
        #pragma unroll
        for (int l = 0; l < NLV; ++l) {
            vf2 v = *(const vf2*)(enc + ((size_t)l * N + i) * 2u);
            e[2 * l + 0] = v[0];
            e[2 * l + 1] = v[1];
        }
        float a0[16];
        #pragma unroll
        for (int j = 0; j < 16; ++j) {
            float s = b0[j];
            #pragma unroll
            for (int k = 0; k < 32; ++k) s += e[k] * W0[j * 32 + k];
            a0[j] = fmaxf(s, 0.f);
        }
        float a1[16];
        #pragma unroll
        for (int j = 0; j < 16; ++j) {
            float s = b1[j];
            #pragma unroll
            for (int k = 0; k < 16; ++k) s += a0[k] * W1[j * 16 + k];
            a1[j] = fmaxf(s, 0.f);
        }
        #pragma unroll
        for (int j = 0; j < 16; ++j) {
            float s = b2[j];
            #pragma unroll
            for (int k = 0; k < 16; ++k) s += a1[k] * W2[j * 16 + k];
            o[j] = s;
        }
    } else {
        #pragma unroll
        for (int j = 0; j < 16; ++j) o[j] = 0.f;
    }

    #pragma unroll
    for (int q = 0; q < 4; ++q) {
        vf4 v; v[0] = o[4*q]; v[1] = o[4*q+1]; v[2] = o[4*q+2]; v[3] = o[4*q+3];
        *(vf4*)&st[t * 17 + 4 * q] = v;
    }
    __syncthreads();

    // 4 lanes per point: each store instruction touches 16 lines, and the 4
    // quarters of each 64B output line merge in L2 (regular stores, no NT).
    const int c = t & 3;
    #pragma unroll
    for (int w = 0; w < 4; ++w) {
        const int p = (t >> 2) + w * 64;      // local point index 0..255
        const int gi = base + p;
        if (gi < N) {
            const int dst = perm[gi];
            const vf4 v = *(const vf4*)&st[p * 17 + 4 * c];
            *(vf4*)(out + 16 * (size_t)dst + 4 * c) = v;
        }
    }
}

// ---------- fallback paths ----------
__global__ __launch_bounds__(256) void encode_coarse_unsorted_kernel(
    const float* __restrict__ x, const float* __restrict__ table,
    float* __restrict__ enc, int N, Scales sc)
{
    int i = blockIdx.x * 256 + threadIdx.x;
    if (i >= N) return;
    const float px = x[3 * (size_t)i + 0];
    const float py = x[3 * (size_t)i + 1];
    const float pz = x[3 * (size_t)i + 2];
    #pragma unroll
    for (int l = 0; l < 5; ++l) {
        float f0, f1;
        enc_level(px, py, pz, sc.s[l], table + (size_t)l * T_SIZE * 2u, f0, f1);
        vf2 v; v[0] = f0; v[1] = f1;
        __builtin_nontemporal_store(v, (vf2*)(enc + ((size_t)l * N + i) * 2u));
    }
}
__global__ __launch_bounds__(256) void encode_one_unsorted_kernel(
    const float* __restrict__ x, const float* __restrict__ tl, float s,
    float* __restrict__ encl, int N)
{
    int i = blockIdx.x * 256 + threadIdx.x;
    if (i >= N) return;
    const float px = x[3 * (size_t)i + 0];
    const float py = x[3 * (size_t)i + 1];
    const float pz = x[3 * (size_t)i + 2];
    float f0, f1;
    enc_level(px, py, pz, s, tl, f0, f1);
    vf2 v; v[0] = f0; v[1] = f1;
    __builtin_nontemporal_store(v, (vf2*)(encl + (size_t)i * 2u));
}
__global__ __launch_bounds__(256) void mlp_noperm_kernel(
    const float* __restrict__ enc,
    const float* __restrict__ W0, const float* __restrict__ b0,
    const float* __restrict__ W1, const float* __restrict__ b1,
    const float* __restrict__ W2, const float* __restrict__ b2,
    float* __restrict__ out, int N)
{
    int i = blockIdx.x * 256 + threadIdx.x;
    if (i >= N) return;
    float e[32];
    #pragma unroll
    for (int l = 0; l < NLV; ++l) {
        vf2 v = *(const vf2*)(enc + ((size_t)l * N + i) * 2u);
        e[2 * l + 0] = v[0];
        e[2 * l + 1] = v[1];
    }
    float a0[16];
    #pragma unroll
    for (int j = 0; j < 16; ++j) {
        float s = b0[j];
        #pragma unroll
        for (int k = 0; k < 32; ++k) s += e[k] * W0[j * 32 + k];
        a0[j] = fmaxf(s, 0.f);
    }
    float a1[16];
    #pragma unroll
    for (int j = 0; j < 16; ++j) {
        float s = b1[j];
        #pragma unroll
        for (int k = 0; k < 16; ++k) s += a0[k] * W1[j * 16 + k];
        a1[j] = fmaxf(s, 0.f);
    }
    #pragma unroll
    for (int j = 0; j < 16; ++j) {
        float s = b2[j];
        #pragma unroll
        for (int k = 0; k < 16; ++k) s += a1[k] * W2[j * 16 + k];
        out[16 * (size_t)i + j] = s;
    }
}
__global__ __launch_bounds__(256) void tcnn_fused_kernel(
    const float* __restrict__ x, const float* __restrict__ table,
    const float* __restrict__ W0, const float* __restrict__ b0,
    const float* __restrict__ W1, const float* __restrict__ b1,
    const float* __restrict__ W2, const float* __restrict__ b2,
    float* __restrict__ out, int N, Scales sc)
{
    int i = blockIdx.x * blockDim.x + threadIdx.x;
    if (i >= N) return;
    const float px = x[3 * (size_t)i + 0];
    const float py = x[3 * (size_t)i + 1];
    const float pz = x[3 * (size_t)i + 2];
    float e[32];
    #pragma unroll
    for (int l = 0; l < NLV; ++l) {
        float f0, f1;
        enc_level(px, py, pz, sc.s[l], table + (size_t)l * T_SIZE * 2u, f0, f1);
        e[2 * l] = f0; e[2 * l + 1] = f1;
    }
    float a0[16];
    #pragma unroll
    for (int j = 0; j < 16; ++j) {
        float s = b0[j];
        #pragma unroll
        for (int k = 0; k < 32; ++k) s += e[k] * W0[j * 32 + k];
        a0[j] = fmaxf(s, 0.f);
    }
    float a1[16];
    #pragma unroll
    for (int j = 0; j < 16; ++j) {
        float s = b1[j];
        #pragma unroll
        for (int k = 0; k < 16; ++k) s += a0[k] * W1[j * 16 + k];
        a1[j] = fmaxf(s, 0.f);
    }
    #pragma unroll
    for (int j = 0; j < 16; ++j) {
        float s = b2[j];
        #pragma unroll
        for (int k = 0; k < 16; ++k) s += a1[k] * W2[j * 16 + k];
        out[16 * (size_t)i + j] = s;
    }
}

extern "C" void kernel_launch(void* const* d_in, const int* in_sizes, int n_in,
                              void* d_out, int out_size, void* d_ws, size_t ws_size,
                              hipStream_t stream) {
    const float* x     = (const float*)d_in[0];
    const float* table = (const float*)d_in[1];
    const float* W0    = (const float*)d_in[2];
    const float* b0    = (const float*)d_in[3];
    const float* W1    = (const float*)d_in[4];
    const float* b1    = (const float*)d_in[5];
    const float* W2    = (const float*)d_in[6];
    const float* b2    = (const float*)d_in[7];
    float* out = (float*)d_out;

    const int N = in_sizes[0] / 3;

    Scales sc;
    const double pls = exp2(log2(2048.0 / 16.0) / 15.0);  // matches numpy double math
    for (int l = 0; l < NLV; ++l) sc.s[l] = (float)(16.0 * pow(pls, (double)l));

    const int block = 256;
    const int grid = (N + block - 1) / block;

    const size_t encB  = (size_t)N * 2u * NLV * sizeof(float);   // 128 MiB
    const size_t xsB   = (size_t)N * sizeof(float) * 4u;         //  16 MiB
    const size_t permB = (size_t)N * sizeof(int);                //   4 MiB
    const size_t histB = (size_t)NBUCK * sizeof(unsigned);

    if (ws_size >= encB + xsB + permB + histB) {
        float*    enc  = (float*)d_ws;
        vf4*      xs   = (vf4*)((char*)d_ws + encB);
        int*      perm = (int*)((char*)d_ws + encB + xsB);
        unsigned* hist = (unsigned*)((char*)d_ws + encB + xsB + permB);

        zero_hist_kernel<<<(NBUCK + 255) / 256, block, 0, stream>>>(hist);
        hist_kernel<<<grid, block, 0, stream>>>(x, hist, N);
        scan_kernel<<<1, 1024, 0, stream>>>(hist);
        scatter_kernel<<<grid, block, 0, stream>>>(x, hist, xs, perm, N);

        encode_coarse_kernel<<<grid, block, 0, stream>>>(xs, table, enc, N, sc);
        const int grid2 = (N + 511) / 512;
        for (int l = 5; l < NLV; ++l) {
            encode_one_kernel<<<grid2, block, 0, stream>>>(
                xs, table + (size_t)l * T_SIZE * 2u, sc.s[l],
                enc + (size_t)l * (size_t)N * 2u, N);
        }
        mlp_kernel<<<grid, block, 0, stream>>>(enc, perm, W0, b0, W1, b1, W2, b2, out, N);
    } else if (ws_size >= encB) {
        float* enc = (float*)d_ws;
        encode_coarse_unsorted_kernel<<<grid, block, 0, stream>>>(x, table, enc, N, sc);
        for (int l = 5; l < NLV; ++l) {
            encode_one_unsorted_kernel<<<grid, block, 0, stream>>>(
                x, table + (size_t)l * T_SIZE * 2u, sc.s[l],
                enc + (size_t)l * (size_t)N * 2u, N);
        }
        mlp_noperm_kernel<<<grid, block, 0, stream>>>(enc, W0, b0, W1, b1, W2, b2, out, N);
    } else {
        tcnn_fused_kernel<<<grid, block, 0, stream>>>(x, table, W0, b0, W1, b1, W2, b2,
                                                      out, N, sc);
    }
}

// Round 5
// 533.131 us; speedup vs baseline: 1.1692x; 1.0238x over previous
//
#include <hip/hip_runtime.h>
#include <math.h>

#define NLV 16
#define LOG2_T 19
#define T_SIZE (1u << LOG2_T)
#define T_MASK (T_SIZE - 1u)
#define P2 2654435761u
#define P3 805459861u
#define NBUCK 32768   // 32^3 Morton buckets

typedef float vf2 __attribute__((ext_vector_type(2)));
typedef float vf4 __attribute__((ext_vector_type(4)));

struct Scales { float s[NLV]; };

// ---------- Morton key (5 bits/axis) ----------
__device__ __forceinline__ unsigned mpart(unsigned v) {
    v = (v | (v << 8)) & 0x100Fu;
    v = (v | (v << 4)) & 0x10C3u;
    v = (v | (v << 2)) & 0x1249u;
    return v;
}
__device__ __forceinline__ unsigned mkey(float px, float py, float pz) {
    unsigned cx = (unsigned)(px * 32.f); cx = cx > 31u ? 31u : cx;
    unsigned cy = (unsigned)(py * 32.f); cy = cy > 31u ? 31u : cy;
    unsigned cz = (unsigned)(pz * 32.f); cz = cz > 31u ? 31u : cz;
    return mpart(cx) | (mpart(cy) << 1) | (mpart(cz) << 2);
}

// ---------- sort kernels ----------
__global__ __launch_bounds__(256) void zero_hist_kernel(unsigned* hist) {
    int i = blockIdx.x * 256 + threadIdx.x;
    if (i < NBUCK) hist[i] = 0u;
}

// 4 points per thread, vectorized x loads.
__global__ __launch_bounds__(256) void hist_kernel(
    const float* __restrict__ x, unsigned* __restrict__ hist, int N)
{
    const int q = blockIdx.x * 256 + threadIdx.x;
    const int i0 = q * 4;
    if (i0 >= N) return;
    if (i0 + 3 < N) {
        const vf4 A = *(const vf4*)(x + 12 * (size_t)q);
        const vf4 B = *(const vf4*)(x + 12 * (size_t)q + 4);
        const vf4 C = *(const vf4*)(x + 12 * (size_t)q + 8);
        const float px[4] = {A[0], A[3], B[2], C[1]};
        const float py[4] = {A[1], B[0], B[3], C[2]};
        const float pz[4] = {A[2], B[1], C[0], C[3]};
        #pragma unroll
        for (int k = 0; k < 4; ++k) atomicAdd(&hist[mkey(px[k], py[k], pz[k])], 1u);
    } else {
        for (int i = i0; i < N; ++i)
            atomicAdd(&hist[mkey(x[3*(size_t)i], x[3*(size_t)i+1], x[3*(size_t)i+2])], 1u);
    }
}

__global__ __launch_bounds__(1024) void scan_kernel(unsigned* hist) {
    __shared__ unsigned tot[1024];
    const int t = threadIdx.x;
    const unsigned base = (unsigned)t * 32u;
    unsigned loc[32];
    unsigned s = 0;
    #pragma unroll
    for (int k = 0; k < 32; ++k) { loc[k] = s; s += hist[base + k]; }
    tot[t] = s;
    __syncthreads();
    for (int off = 1; off < 1024; off <<= 1) {
        unsigned u = (t >= off) ? tot[t - off] : 0u;
        __syncthreads();
        tot[t] += u;
        __syncthreads();
    }
    const unsigned excl = tot[t] - s;
    #pragma unroll
    for (int k = 0; k < 32; ++k) hist[base + k] = excl + loc[k];
}

__global__ __launch_bounds__(256) void scatter_kernel(
    const float* __restrict__ x, unsigned* __restrict__ cursor,
    vf4* __restrict__ xs, int* __restrict__ perm, int N)
{
    const int q = blockIdx.x * 256 + threadIdx.x;
    const int i0 = q * 4;
    if (i0 >= N) return;
    if (i0 + 3 < N) {
        const vf4 A = *(const vf4*)(x + 12 * (size_t)q);
        const vf4 B = *(const vf4*)(x + 12 * (size_t)q + 4);
        const vf4 C = *(const vf4*)(x + 12 * (size_t)q + 8);
        const float px[4] = {A[0], A[3], B[2], C[1]};
        const float py[4] = {A[1], B[0], B[3], C[2]};
        const float pz[4] = {A[2], B[1], C[0], C[3]};
        #pragma unroll
        for (int k = 0; k < 4; ++k) {
            const unsigned key = mkey(px[k], py[k], pz[k]);
            const unsigned pos = atomicAdd(&cursor[key], 1u);
            vf4 v; v[0] = px[k]; v[1] = py[k]; v[2] = pz[k]; v[3] = 0.f;
            xs[pos] = v;
            perm[pos] = i0 + k;
        }
    } else {
        for (int i = i0; i < N; ++i) {
            const float px = x[3*(size_t)i], py = x[3*(size_t)i+1], pz = x[3*(size_t)i+2];
            const unsigned key = mkey(px, py, pz);
            const unsigned pos = atomicAdd(&cursor[key], 1u);
            vf4 v; v[0] = px; v[1] = py; v[2] = pz; v[3] = 0.f;
            xs[pos] = v;
            perm[pos] = i;
        }
    }
}

// ---------- encode ----------
__device__ __forceinline__ void enc_level(
    float px, float py, float pz, float s, const float* __restrict__ tl,
    float& f0, float& f1)
{
    const float fx = px * s, fy = py * s, fz = pz * s;
    const float bx = floorf(fx), by = floorf(fy), bz = floorf(fz);
    const float rx = fx - bx, ry = fy - by, rz = fz - bz;
    const unsigned ix0 = (unsigned)bx, iy0 = (unsigned)by, iz0 = (unsigned)bz;
    const unsigned hx0 = ix0,      hx1 = ix0 + 1u;
    const unsigned hy0 = iy0 * P2, hy1 = (iy0 + 1u) * P2;
    const unsigned hz0 = iz0 * P3, hz1 = (iz0 + 1u) * P3;
    const float wx0 = 1.f - rx, wy0 = 1.f - ry, wz0 = 1.f - rz;
    f0 = 0.f; f1 = 0.f;
    #pragma unroll
    for (int c = 0; c < 8; ++c) {
        unsigned h = ((c & 4) ? hx1 : hx0) ^ ((c & 2) ? hy1 : hy0) ^ ((c & 1) ? hz1 : hz0);
        h &= T_MASK;
        const vf2 f = *(const vf2*)(tl + 2u * (size_t)h);
        const float w = ((c & 4) ? rx : wx0) * ((c & 2) ? ry : wy0) * ((c & 1) ? rz : wz0);
        f0 += w * f[0];
        f1 += w * f[1];
    }
}

// Levels 0..4 fused (working sets co-resident in L2). Plain stores: enc stays in L2/L3.
__global__ __launch_bounds__(256) void encode_coarse_kernel(
    const vf4* __restrict__ xs, const float* __restrict__ table,
    float* __restrict__ enc, int N, Scales sc)
{
    int i = blockIdx.x * 256 + threadIdx.x;
    if (i >= N) return;
    const vf4 p = xs[i];
    #pragma unroll
    for (int l = 0; l < 5; ++l) {
        float f0, f1;
        enc_level(p[0], p[1], p[2], sc.s[l], table + (size_t)l * T_SIZE * 2u, f0, f1);
        vf2 v; v[0] = f0; v[1] = f1;
        *(vf2*)(enc + ((size_t)l * N + i) * 2u) = v;
    }
}

// One fine level per launch; 4 points per thread for memory-level parallelism.
__global__ __launch_bounds__(256) void encode_one_kernel(
    const vf4* __restrict__ xs, const float* __restrict__ tl, float s,
    float* __restrict__ encl, int N)
{
    const int i0 = blockIdx.x * 1024 + threadIdx.x;
    #pragma unroll
    for (int k = 0; k < 4; ++k) {
        const int i = i0 + k * 256;
        if (i < N) {
            const vf4 p = xs[i];
            float f0, f1;
            enc_level(p[0], p[1], p[2], s, tl, f0, f1);
            vf2 v; v[0] = f0; v[1] = f1;
            *(vf2*)(encl + (size_t)i * 2u) = v;
        }
    }
}

// ---------- MLP: 2 points/thread, vf4 enc loads, LDS-staged cooperative store ----------
__global__ __launch_bounds__(256) void mlp_kernel(
    const float* __restrict__ enc, const int* __restrict__ perm,
    const float* __restrict__ W0, const float* __restrict__ b0,
    const float* __restrict__ W1, const float* __restrict__ b1,
    const float* __restrict__ W2, const float* __restrict__ b2,
    float* __restrict__ out, int N)
{
    __shared__ float st[512 * 17];   // 34816 B
    const int base = blockIdx.x * 512;
    const int t = threadIdx.x;
    const int p0 = base + 2 * t;

    if (p0 < N) {
        // e layout per level l: [f0(p0), f1(p0), f0(p1), f1(p1)]
        // NOTE: when p0+1==N the vf4 read overruns enc by 8B into the adjacent
        // ws region (xs) — allocated memory, value unused (guarded below).
        float e[64];
        #pragma unroll
        for (int l = 0; l < NLV; ++l) {
            vf4 v = *(const vf4*)(enc + ((size_t)l * N + p0) * 2u);
            e[4*l+0] = v[0]; e[4*l+1] = v[1]; e[4*l+2] = v[2]; e[4*l+3] = v[3];
        }
        #pragma unroll
        for (int q = 0; q < 2; ++q) {
            if (q == 0 || p0 + 1 < N) {
                float a0[16];
                #pragma unroll
                for (int j = 0; j < 16; ++j) {
                    float s = b0[j];
                    #pragma unroll
                    for (int l = 0; l < NLV; ++l) {
                        s += e[4*l + 2*q + 0] * W0[j * 32 + 2*l + 0];
                        s += e[4*l + 2*q + 1] * W0[j * 32 + 2*l + 1];
                    }
                    a0[j] = fmaxf(s, 0.f);
                }
                float a1[16];
                #pragma unroll
                for (int j = 0; j < 16; ++j) {
                    float s = b1[j];
                    #pragma unroll
                    for (int k = 0; k < 16; ++k) s += a0[k] * W1[j * 16 + k];
                    a1[j] = fmaxf(s, 0.f);
                }
                const int row = 2 * t + q;
                #pragma unroll
                for (int j = 0; j < 16; ++j) {
                    float s = b2[j];
                    #pragma unroll
                    for (int k = 0; k < 16; ++k) s += a1[k] * W2[j * 16 + k];
                    st[row * 17 + j] = s;
                }
            }
        }
    }
    __syncthreads();

    // 4 lanes per point: each store instruction touches 16 lines; the 4
    // quarters of each 64B output line merge in L2.
    const int c = t & 3;
    #pragma unroll
    for (int w = 0; w < 8; ++w) {
        const int p = (t >> 2) + w * 64;      // local point index 0..511
        const int gi = base + p;
        if (gi < N) {
            const int dst = perm[gi];
            const vf4 v = *(const vf4*)&st[p * 17 + 4 * c];
            *(vf4*)(out + 16 * (size_t)dst + 4 * c) = v;
        }
    }
}

// ---------- fallback paths ----------
__global__ __launch_bounds__(256) void encode_coarse_unsorted_kernel(
    const float* __restrict__ x, const float* __restrict__ table,
    float* __restrict__ enc, int N, Scales sc)
{
    int i = blockIdx.x * 256 + threadIdx.x;
    if (i >= N) return;
    const float px = x[3 * (size_t)i + 0];
    const float py = x[3 * (size_t)i + 1];
    const float pz = x[3 * (size_t)i + 2];
    #pragma unroll
    for (int l = 0; l < 5; ++l) {
        float f0, f1;
        enc_level(px, py, pz, sc.s[l], table + (size_t)l * T_SIZE * 2u, f0, f1);
        vf2 v; v[0] = f0; v[1] = f1;
        *(vf2*)(enc + ((size_t)l * N + i) * 2u) = v;
    }
}
__global__ __launch_bounds__(256) void encode_one_unsorted_kernel(
    const float* __restrict__ x, const float* __restrict__ tl, float s,
    float* __restrict__ encl, int N)
{
    int i = blockIdx.x * 256 + threadIdx.x;
    if (i >= N) return;
    const float px = x[3 * (size_t)i + 0];
    const float py = x[3 * (size_t)i + 1];
    const float pz = x[3 * (size_t)i + 2];
    float f0, f1;
    enc_level(px, py, pz, s, tl, f0, f1);
    vf2 v; v[0] = f0; v[1] = f1;
    *(vf2*)(encl + (size_t)i * 2u) = v;
}
__global__ __launch_bounds__(256) void mlp_noperm_kernel(
    const float* __restrict__ enc,
    const float* __restrict__ W0, const float* __restrict__ b0,
    const float* __restrict__ W1, const float* __restrict__ b1,
    const float* __restrict__ W2, const float* __restrict__ b2,
    float* __restrict__ out, int N)
{
    int i = blockIdx.x * 256 + threadIdx.x;
    if (i >= N) return;
    float e[32];
    #pragma unroll
    for (int l = 0; l < NLV; ++l) {
        vf2 v = *(const vf2*)(enc + ((size_t)l * N + i) * 2u);
        e[2 * l + 0] = v[0];
        e[2 * l + 1] = v[1];
    }
    float a0[16];
    #pragma unroll
    for (int j = 0; j < 16; ++j) {
        float s = b0[j];
        #pragma unroll
        for (int k = 0; k < 32; ++k) s += e[k] * W0[j * 32 + k];
        a0[j] = fmaxf(s, 0.f);
    }
    float a1[16];
    #pragma unroll
    for (int j = 0; j < 16; ++j) {
        float s = b1[j];
        #pragma unroll
        for (int k = 0; k < 16; ++k) s += a0[k] * W1[j * 16 + k];
        a1[j] = fmaxf(s, 0.f);
    }
    #pragma unroll
    for (int j = 0; j < 16; ++j) {
        float s = b2[j];
        #pragma unroll
        for (int k = 0; k < 16; ++k) s += a1[k] * W2[j * 16 + k];
        out[16 * (size_t)i + j] = s;
    }
}
__global__ __launch_bounds__(256) void tcnn_fused_kernel(
    const float* __restrict__ x, const float* __restrict__ table,
    const float* __restrict__ W0, const float* __restrict__ b0,
    const float* __restrict__ W1, const float* __restrict__ b1,
    const float* __restrict__ W2, const float* __restrict__ b2,
    float* __restrict__ out, int N, Scales sc)
{
    int i = blockIdx.x * blockDim.x + threadIdx.x;
    if (i >= N) return;
    const float px = x[3 * (size_t)i + 0];
    const float py = x[3 * (size_t)i + 1];
    const float pz = x[3 * (size_t)i + 2];
    float e[32];
    #pragma unroll
    for (int l = 0; l < NLV; ++l) {
        float f0, f1;
        enc_level(px, py, pz, sc.s[l], table + (size_t)l * T_SIZE * 2u, f0, f1);
        e[2 * l] = f0; e[2 * l + 1] = f1;
    }
    float a0[16];
    #pragma unroll
    for (int j = 0; j < 16; ++j) {
        float s = b0[j];
        #pragma unroll
        for (int k = 0; k < 32; ++k) s += e[k] * W0[j * 32 + k];
        a0[j] = fmaxf(s, 0.f);
    }
    float a1[16];
    #pragma unroll
    for (int j = 0; j < 16; ++j) {
        float s = b1[j];
        #pragma unroll
        for (int k = 0; k < 16; ++k) s += a0[k] * W1[j * 16 + k];
        a1[j] = fmaxf(s, 0.f);
    }
    #pragma unroll
    for (int j = 0; j < 16; ++j) {
        float s = b2[j];
        #pragma unroll
        for (int k = 0; k < 16; ++k) s += a1[k] * W2[j * 16 + k];
        out[16 * (size_t)i + j] = s;
    }
}

extern "C" void kernel_launch(void* const* d_in, const int* in_sizes, int n_in,
                              void* d_out, int out_size, void* d_ws, size_t ws_size,
                              hipStream_t stream) {
    const float* x     = (const float*)d_in[0];
    const float* table = (const float*)d_in[1];
    const float* W0    = (const float*)d_in[2];
    const float* b0    = (const float*)d_in[3];
    const float* W1    = (const float*)d_in[4];
    const float* b1    = (const float*)d_in[5];
    const float* W2    = (const float*)d_in[6];
    const float* b2    = (const float*)d_in[7];
    float* out = (float*)d_out;

    const int N = in_sizes[0] / 3;

    Scales sc;
    const double pls = exp2(log2(2048.0 / 16.0) / 15.0);  // matches numpy double math
    for (int l = 0; l < NLV; ++l) sc.s[l] = (float)(16.0 * pow(pls, (double)l));

    const int block = 256;
    const int grid = (N + block - 1) / block;

    const size_t encB  = (size_t)N * 2u * NLV * sizeof(float);   // 128 MiB
    const size_t xsB   = (size_t)N * sizeof(float) * 4u;         //  16 MiB
    const size_t permB = (size_t)N * sizeof(int);                //   4 MiB
    const size_t histB = (size_t)NBUCK * sizeof(unsigned);

    if (ws_size >= encB + xsB + permB + histB) {
        float*    enc  = (float*)d_ws;
        vf4*      xs   = (vf4*)((char*)d_ws + encB);
        int*      perm = (int*)((char*)d_ws + encB + xsB);
        unsigned* hist = (unsigned*)((char*)d_ws + encB + xsB + permB);

        const int gridQ = (N + 1023) / 1024;   // 4 pts/thread kernels
        zero_hist_kernel<<<(NBUCK + 255) / 256, block, 0, stream>>>(hist);
        hist_kernel<<<gridQ, block, 0, stream>>>(x, hist, N);
        scan_kernel<<<1, 1024, 0, stream>>>(hist);
        scatter_kernel<<<gridQ, block, 0, stream>>>(x, hist, xs, perm, N);

        encode_coarse_kernel<<<grid, block, 0, stream>>>(xs, table, enc, N, sc);
        for (int l = 5; l < NLV; ++l) {
            encode_one_kernel<<<gridQ, block, 0, stream>>>(
                xs, table + (size_t)l * T_SIZE * 2u, sc.s[l],
                enc + (size_t)l * (size_t)N * 2u, N);
        }
        const int gridM = (N + 511) / 512;     // 2 pts/thread MLP
        mlp_kernel<<<gridM, block, 0, stream>>>(enc, perm, W0, b0, W1, b1, W2, b2, out, N);
    } else if (ws_size >= encB) {
        float* enc = (float*)d_ws;
        encode_coarse_unsorted_kernel<<<grid, block, 0, stream>>>(x, table, enc, N, sc);
        for (int l = 5; l < NLV; ++l) {
            encode_one_unsorted_kernel<<<grid, block, 0, stream>>>(
                x, table + (size_t)l * T_SIZE * 2u, sc.s[l],
                enc + (size_t)l * (size_t)N * 2u, N);
        }
        mlp_noperm_kernel<<<grid, block, 0, stream>>>(enc, W0, b0, W1, b1, W2, b2, out, N);
    } else {
        tcnn_fused_kernel<<<grid, block, 0, stream>>>(x, table, W0, b0, W1, b1, W2, b2,
                                                      out, N, sc);
    }
}